// Round 3
// baseline (189.733 us; speedup 1.0000x reference)
//
#include <hip/hip_runtime.h>
#include <math.h>

typedef unsigned short ushort_t;
typedef unsigned int uint_t;
typedef unsigned long long u64_t;
typedef __attribute__((ext_vector_type(8))) __bf16 bf16x8;
typedef __attribute__((ext_vector_type(4))) float f32x4;

#define NN 4096
#define TT 5
#define F1 32
#define F2 64

// round-to-nearest-even fp32 -> bf16 bits
__device__ __forceinline__ ushort_t f2bf(float x) {
    union { float f; uint_t u; } v; v.f = x;
    uint_t r = (v.u + 0x7FFFu + ((v.u >> 16) & 1u)) >> 16;
    return (ushort_t)r;
}
__device__ __forceinline__ uint_t pk2(float a, float b) {
    return (uint_t)f2bf(a) | ((uint_t)f2bf(b) << 16);
}
// fast tanh: (e^2x - 1)/(e^2x + 1), clamped; err ~1e-6 (irrelevant vs bf16 noise)
__device__ __forceinline__ float tanh_fast(float x) {
    const float xc = fminf(fmaxf(x, -10.f), 10.f);
    const float e = __expf(2.f * xc);
    return (e - 1.f) * __builtin_amdgcn_rcpf(e + 1.f);
}

// ---------------- K0: weight pre-transpose to bf16 + zero colbits ------------------------
__global__ __launch_bounds__(256) void k0_prep(
    const float* __restrict__ Wc2, const float* __restrict__ Wg1, const float* __restrict__ Wd,
    ushort_t* __restrict__ Wc2T_ws, ushort_t* __restrict__ WgT_ws, ushort_t* __restrict__ WdT_ws,
    uint_t* __restrict__ colbits)
{
    const int blk = blockIdx.x, t = threadIdx.x;
    if (blk == 0) {
        if (t < 32) ((uint4*)colbits)[t] = make_uint4(0, 0, 0, 0);   // 512 B
    } else if (blk == 1) {          // Wc2 [96][64] -> Wc2T_ws[f*96 + e]
        for (int i = t; i < 6144; i += 256) {
            const int e = i >> 6, f = i & 63;
            Wc2T_ws[f * 96 + e] = f2bf(Wc2[i]);
        }
    } else if (blk == 2) {          // Wg1 [64][64] -> WgT_ws[o*64 + in]
        for (int i = t; i < 4096; i += 256) {
            const int in = i >> 6, o = i & 63;
            WgT_ws[o * 64 + in] = f2bf(Wg1[i]);
        }
    } else {                        // Wd [128][64] -> WdT_ws[o*128 + in]
        for (int i = t; i < 8192; i += 256) {
            const int in = i >> 6, o = i & 63;
            WdT_ws[o * 128 + in] = f2bf(Wd[i]);
        }
    }
}

// ---------------- K2: perfect-sweep edges -> bits + deg + colbits + diag ----------------
// 512 blocks x 1024 thr, 8 grid-stride steps. At each step the whole chip reads ONE
// contiguous 8 MiB slab (1 KiB per wave-instr, lane-contiguous) — the m13/fill pattern
// that measures 6.3+ TB/s. All 8 int4 loads issued up-front (32 VGPRs in flight).
// Per step a block covers exactly one 16 KiB row: bit-pack via 3 shfl_xor ORs in 8-lane
// groups; deg = one block reduction + PLAIN store (no atomics, no zero pass); colbits
// accumulated in-register across the 8 rows; diag read off the assembled word.
__global__ __launch_bounds__(1024, 4) void k2_bits(
    const int4* __restrict__ edges4, uint_t* __restrict__ bits,
    int* __restrict__ degI, uint_t* __restrict__ colbits, unsigned char* __restrict__ diagB)
{
    const int t = threadIdx.x;
    const int bid = blockIdx.x;
    __shared__ int sdeg[16][8];

    int4 v[8];
    #pragma unroll
    for (int s = 0; s < 8; ++s)
        v[s] = edges4[(size_t)s * 524288 + (size_t)bid * 1024 + (size_t)t];

    const int w = t >> 6, l = t & 63;
    const int nsh = (t & 7) * 4;
    uint_t creg = 0;
    #pragma unroll
    for (int s = 0; s < 8; ++s) {
        const int row = s * 512 + bid;
        const uint_t nib = (v[s].x != 0 ? 1u : 0u) | (v[s].y != 0 ? 2u : 0u) |
                           (v[s].z != 0 ? 4u : 0u) | (v[s].w != 0 ? 8u : 0u);
        uint_t part = nib << nsh;
        part |= __shfl_xor(part, 1);
        part |= __shfl_xor(part, 2);
        part |= __shfl_xor(part, 4);
        // lane (t&7)==0 now holds the 32-bit word for columns [(t>>3)*32, +32) of this row
        if ((t & 7) == 0) {
            bits[(size_t)row * 128 + (size_t)(t >> 3)] = part;
            creg |= part;
            if ((t >> 3) == (row >> 5))
                diagB[row] = (unsigned char)((part >> (row & 31)) & 1u);
        }
        int p = __popc(nib);
        #pragma unroll
        for (int off = 32; off >= 1; off >>= 1) p += __shfl_down(p, off);
        if (l == 0) sdeg[w][s] = p;
    }
    __syncthreads();
    if (t < 8) {
        int s2 = 0;
        #pragma unroll
        for (int w2 = 0; w2 < 16; ++w2) s2 += sdeg[w2][t];
        degI[t * 512 + bid] = s2;       // unique row per (block,step): plain store
    }
    if ((t & 7) == 0) atomicOr(&colbits[t >> 3], creg);
}

// ---------------- K1: conv1 (VALU) + conv2 (MFMA) -> condT (col-major) + condB (row-major)
#define H1S 104
#define CBS 80
__global__ __launch_bounds__(256) void k1_cond(
    const float* __restrict__ ts, const float* __restrict__ Wc1, const float* __restrict__ bc1,
    const ushort_t* __restrict__ Wc2T_ws, const float* __restrict__ bc2,
    ushort_t* __restrict__ condT, ushort_t* __restrict__ condB)
{
    const int b = blockIdx.y;
    const int j0 = blockIdx.x * 64;
    const int t = threadIdx.x;

    __shared__ float sWc1[384];
    __shared__ float sbc1[F1];
    __shared__ float sbc2[F2];
    __shared__ ushort_t sWc2T[64 * H1S];
    __shared__ ushort_t h1B[64 * H1S];
    __shared__ ushort_t scb[64 * CBS];

    for (int i = t; i < 384; i += 256) sWc1[i] = Wc1[i];
    if (t < F1) sbc1[t] = bc1[t];
    if (t < F2) sbc2[t] = bc2[t];
    for (int i = t; i < 768; i += 256) {
        const int f = i / 12, c = i - f * 12;
        *(uint4*)&sWc2T[f * H1S + c * 8] = *(const uint4*)(Wc2T_ws + f * 96 + c * 8);
    }
    __syncthreads();

    {   // phase A: h1 = relu(conv1)
        const int n = t & 63, f10 = (t >> 6) * 8;
        const int j = j0 + n;
        float4 x[5];
        #pragma unroll
        for (int tt = 0; tt < 5; ++tt)
            x[tt] = *(const float4*)(ts + ((((size_t)b * TT + tt) << 12) + j) * 4);
        #pragma unroll
        for (int tt0 = 0; tt0 < 3; ++tt0) {
            #pragma unroll
            for (int ff = 0; ff < 8; ++ff) {
                const int f1 = f10 + ff;
                float a = sbc1[f1];
                #pragma unroll
                for (int dt = 0; dt < 3; ++dt) {
                    const float4 xx = x[tt0 + dt];
                    a += xx.x * sWc1[(dt * 4 + 0) * F1 + f1];
                    a += xx.y * sWc1[(dt * 4 + 1) * F1 + f1];
                    a += xx.z * sWc1[(dt * 4 + 2) * F1 + f1];
                    a += xx.w * sWc1[(dt * 4 + 3) * F1 + f1];
                }
                h1B[n * H1S + tt0 * 32 + f1] = f2bf(fmaxf(a, 0.f));
            }
        }
    }
    __syncthreads();

    {   // phase B: cond = h1 @ Wc2 + bc2 via MFMA
        const int w = t >> 6, l = t & 63;
        const int m0 = w * 16, kseg = (l >> 4) * 8;
        f32x4 acc[4] = {};
        #pragma unroll
        for (int ks = 0; ks < 3; ++ks) {
            const bf16x8 av = *(const bf16x8*)&h1B[(m0 + (l & 15)) * H1S + ks * 32 + kseg];
            #pragma unroll
            for (int ct = 0; ct < 4; ++ct) {
                const bf16x8 bv = *(const bf16x8*)&sWc2T[(ct * 16 + (l & 15)) * H1S + ks * 32 + kseg];
                acc[ct] = __builtin_amdgcn_mfma_f32_16x16x32_bf16(av, bv, acc[ct], 0, 0, 0);
            }
        }
        #pragma unroll
        for (int ct = 0; ct < 4; ++ct)
            #pragma unroll
            for (int i = 0; i < 4; ++i) {
                const int row = m0 + (l >> 4) * 4 + i;
                const int col = ct * 16 + (l & 15);
                scb[col * CBS + row] = f2bf(acc[ct][i] + sbc2[col]);
            }
    }
    __syncthreads();
    {   // condT writeback (col-major [f][j])
        const int f2 = t >> 2, seg = t & 3;
        ushort_t* dst = condT + (((size_t)b * 64 + f2) << 12) + j0 + seg * 16;
        *(uint4*)dst = *(const uint4*)&scb[f2 * CBS + seg * 16];
        *(uint4*)(dst + 8) = *(const uint4*)&scb[f2 * CBS + seg * 16 + 8];
    }
    {   // condB writeback (row-major [j][f]) — transpose read from scb
        const int r = t >> 2, q = t & 3;
        uint_t u[8];
        #pragma unroll
        for (int k = 0; k < 8; ++k)
            u[k] = (uint_t)scb[(q * 16 + 2 * k) * CBS + r] |
                   ((uint_t)scb[(q * 16 + 2 * k + 1) * CBS + r] << 16);
        ushort_t* dstB = condB + ((((size_t)b << 12) + j0 + r) << 6) + q * 16;
        *(uint4*)dstB = make_uint4(u[0], u[1], u[2], u[3]);
        *(uint4*)(dstB + 8) = make_uint4(u[4], u[5], u[6], u[7]);
    }
}

// ---------------- K3: bit-staged adjacency GEMM (pure) -----------------------------------
// grid 512 = 128 row-stripes(32r) x 4 k-splits(1024); 1024 thr (16 waves), 2 blocks/CU.
// A-tile staging: 1 uint of bits per thread (4 KB/block from L2), expanded in-register to
// bf16 {0,1} into the swizzled LDS layout the MFMA loop reads. Single barrier.
__global__ __launch_bounds__(1024, 8) void k3_gemm(
    const uint_t* __restrict__ bits, const ushort_t* __restrict__ condT,
    float* __restrict__ agg0, float* __restrict__ agg1,
    float* __restrict__ agg2, float* __restrict__ agg3)
{
    const int t = threadIdx.x;
    const int stripe = blockIdx.x >> 2, ks4 = blockIdx.x & 3;
    const int j0 = stripe * 32, kb = ks4 * 1024;

    __shared__ __align__(16) ushort_t abuf[8][4096];   // 64 KB: 8 chunks x (32r x 128k)

    // staging map: t = rh*512 + wq*16 + rl  (16 distinct rl per wave -> conflict-free writes)
    const int rl = t & 15, wq = (t >> 4) & 31, rh = t >> 9;
    const uint_t bw = bits[(size_t)(j0 + rh * 16 + rl) * 128 + (size_t)(kb >> 5) + (size_t)wq];
    {
        // word wq covers chunk wq>>2, k-seg wq&3; storage index matches the aoff read:
        // addr(rh,rl,ks,o,w) = rh*2048 + ks*512 + o*128 + ((rl*8)^(o<<4)) + w
        ushort_t* dst = &abuf[wq >> 2][rh * 2048 + (wq & 3) * 512];
        #pragma unroll
        for (int o = 0; o < 4; ++o) {
            const uint_t oct = bw >> (o * 8);
            uint4 wv;
            wv.x = ((oct & 1u)   ? 0x3F80u : 0u) | ((oct & 2u)   ? 0x3F800000u : 0u);
            wv.y = ((oct & 4u)   ? 0x3F80u : 0u) | ((oct & 8u)   ? 0x3F800000u : 0u);
            wv.z = ((oct & 16u)  ? 0x3F80u : 0u) | ((oct & 32u)  ? 0x3F800000u : 0u);
            wv.w = ((oct & 64u)  ? 0x3F80u : 0u) | ((oct & 128u) ? 0x3F800000u : 0u);
            *(uint4*)(dst + o * 128 + ((rl * 8) ^ (o << 4))) = wv;
        }
    }
    __syncthreads();

    const int w = t >> 6, l = t & 63;
    const int aoff = (l * 8) ^ ((l >> 4) << 4);
    const ushort_t* bp = condT + (size_t)(w * 16 + (l & 15)) * NN + kb + (l >> 4) * 8;

    f32x4 acc0 = {0.f, 0.f, 0.f, 0.f};
    f32x4 acc1 = {0.f, 0.f, 0.f, 0.f};

    #pragma unroll
    for (int ch = 0; ch < 8; ++ch) {
        const ushort_t* ab = &abuf[ch][0];
        const ushort_t* bpi = bp + ch * 128;
        #pragma unroll
        for (int ks = 0; ks < 4; ++ks) {
            const bf16x8 bfv = *(const bf16x8*)(bpi + ks * 32);
            const bf16x8 a0 = *(const bf16x8*)(ab + ks * 512 + aoff);
            const bf16x8 a1 = *(const bf16x8*)(ab + 2048 + ks * 512 + aoff);
            acc0 = __builtin_amdgcn_mfma_f32_16x16x32_bf16(a0, bfv, acc0, 0, 0, 0);
            acc1 = __builtin_amdgcn_mfma_f32_16x16x32_bf16(a1, bfv, acc1, 0, 0, 0);
        }
    }

    // epilogue: plain stores to this split's slab
    {
        float* aggS = (ks4 == 0) ? agg0 : (ks4 == 1) ? agg1 : (ks4 == 2) ? agg2 : agg3;
        const int col = w * 16 + (l & 15);
        float* dst = aggS + ((size_t)(col >> 6) * NN << 6) + (col & 63);
        #pragma unroll
        for (int i = 0; i < 4; ++i) {
            const int ja = j0 + (l >> 4) * 4 + i;
            dst[(size_t)ja << 6] = acc0[i];
            dst[(size_t)(ja + 16) << 6] = acc1[i];
        }
    }
}

// ---------------- K4: MLP epilogue on MFMA; 64 rows/block, grid (64,4) -------------------
#define WGS 88
#define WDS 136
#define HS  69
__global__ __launch_bounds__(256) void k4_mlp(
    const float* __restrict__ ts, const ushort_t* __restrict__ condB,
    const float* __restrict__ agg0, const float* __restrict__ agg1,
    const float* __restrict__ agg2, const float* __restrict__ agg3,
    const int* __restrict__ degI, const uint_t* __restrict__ colbits,
    const unsigned char* __restrict__ diagB,
    const ushort_t* __restrict__ WgT_ws, const float* __restrict__ bg,
    const ushort_t* __restrict__ WdT_ws, const float* __restrict__ bd,
    const float* __restrict__ Wo, const float* __restrict__ bo,
    float* __restrict__ out)
{
    const int b = blockIdx.y;
    const int j0 = blockIdx.x * 64;
    const int t = threadIdx.x;

    __shared__ ushort_t sWg1T[64 * WGS];
    __shared__ ushort_t sWdT[64 * WDS];
    __shared__ ushort_t aggB[64 * WGS];
    __shared__ ushort_t catB[64 * WDS];
    __shared__ float sH[64 * HS];
    __shared__ float sWo[256];
    __shared__ float sbg[64], sbd[64], sbo[4], sAlive[64];

    for (int i = t; i < 512; i += 256)
        *(uint4*)&sWg1T[(i >> 3) * WGS + (i & 7) * 8] = ((const uint4*)WgT_ws)[i];
    for (int i = t; i < 1024; i += 256)
        *(uint4*)&sWdT[(i >> 4) * WDS + (i & 15) * 8] = ((const uint4*)WdT_ws)[i];
    if (t < 256) sWo[t] = Wo[t];
    if (t < 64) { sbg[t] = bg[t]; sbd[t] = bd[t]; }
    if (t < 4) sbo[t] = bo[t];
    if (t < 64) {
        const int j = j0 + t;
        sAlive[t] = (float)((colbits[j >> 5] >> (j & 31)) & 1u);
    }
    {   // phase 0: aggN = (sum slabs - diag*cond_bf16)/deg -> bf16; catB = cond_bf16 copy
        const int r = t >> 2, fs = t & 3;
        const int j = j0 + r;
        const float dv = (float)degI[j];
        const float inv = 1.f / (dv > 0.f ? dv : 1.f);
        const float dgf = (float)diagB[j];
        const size_t base = (((size_t)b << 12) + j) << 6;
        const uint4 c0 = *(const uint4*)(condB + base + fs * 16);
        const uint4 c1 = *(const uint4*)(condB + base + fs * 16 + 8);
        *(uint4*)&catB[r * WDS + fs * 16] = c0;
        *(uint4*)&catB[r * WDS + fs * 16 + 8] = c1;
        #pragma unroll
        for (int q = 0; q < 4; ++q) {
            uint_t wlo, whi;
            if (q == 0)      { wlo = c0.x; whi = c0.y; }
            else if (q == 1) { wlo = c0.z; whi = c0.w; }
            else if (q == 2) { wlo = c1.x; whi = c1.y; }
            else             { wlo = c1.z; whi = c1.w; }
            const int f = fs * 16 + q * 4;
            const float4 a0 = *(const float4*)(agg0 + base + f);
            const float4 a1 = *(const float4*)(agg1 + base + f);
            const float4 a2 = *(const float4*)(agg2 + base + f);
            const float4 a3 = *(const float4*)(agg3 + base + f);
            const float cv0 = __uint_as_float(wlo << 16);
            const float cv1 = __uint_as_float(wlo & 0xFFFF0000u);
            const float cv2 = __uint_as_float(whi << 16);
            const float cv3 = __uint_as_float(whi & 0xFFFF0000u);
            const float n0 = (a0.x + a1.x + a2.x + a3.x - dgf * cv0) * inv;
            const float n1 = (a0.y + a1.y + a2.y + a3.y - dgf * cv1) * inv;
            const float n2 = (a0.z + a1.z + a2.z + a3.z - dgf * cv2) * inv;
            const float n3 = (a0.w + a1.w + a2.w + a3.w - dgf * cv3) * inv;
            *(uint2*)&aggB[r * WGS + f] = make_uint2(pk2(n0, n1), pk2(n2, n3));
        }
    }
    __syncthreads();

    const int w = t >> 6, l = t & 63;
    const int m0 = w * 16, kseg = (l >> 4) * 8;

    {   // phase G
        f32x4 acc[4] = {};
        #pragma unroll
        for (int ks = 0; ks < 2; ++ks) {
            const bf16x8 av = *(const bf16x8*)&aggB[(m0 + (l & 15)) * WGS + ks * 32 + kseg];
            #pragma unroll
            for (int ct = 0; ct < 4; ++ct) {
                const bf16x8 bv = *(const bf16x8*)&sWg1T[(ct * 16 + (l & 15)) * WGS + ks * 32 + kseg];
                acc[ct] = __builtin_amdgcn_mfma_f32_16x16x32_bf16(av, bv, acc[ct], 0, 0, 0);
            }
        }
        #pragma unroll
        for (int ct = 0; ct < 4; ++ct)
            #pragma unroll
            for (int i = 0; i < 4; ++i) {
                const int row = m0 + (l >> 4) * 4 + i;
                const int col = ct * 16 + (l & 15);
                const float g = tanh_fast(acc[ct][i] + sbg[col]) * sAlive[row];
                catB[row * WDS + 64 + col] = f2bf(g);
            }
    }
    __syncthreads();
    {   // phase H
        f32x4 acc[4] = {};
        #pragma unroll
        for (int ks = 0; ks < 4; ++ks) {
            const bf16x8 av = *(const bf16x8*)&catB[(m0 + (l & 15)) * WDS + ks * 32 + kseg];
            #pragma unroll
            for (int ct = 0; ct < 4; ++ct) {
                const bf16x8 bv = *(const bf16x8*)&sWdT[(ct * 16 + (l & 15)) * WDS + ks * 32 + kseg];
                acc[ct] = __builtin_amdgcn_mfma_f32_16x16x32_bf16(av, bv, acc[ct], 0, 0, 0);
            }
        }
        #pragma unroll
        for (int ct = 0; ct < 4; ++ct)
            #pragma unroll
            for (int i = 0; i < 4; ++i) {
                const int row = m0 + (l >> 4) * 4 + i;
                const int col = ct * 16 + (l & 15);
                sH[row * HS + col] = fmaxf(acc[ct][i] + sbd[col], 0.f);
            }
    }
    __syncthreads();
    {   // phase O
        const int r = t >> 2, d = t & 3;
        const int j = j0 + r;
        float s = sbo[d];
        #pragma unroll 8
        for (int f = 0; f < 64; ++f) s += sH[r * HS + f] * sWo[f * 4 + d];
        const float segl = ts[((((size_t)b * TT + 4) << 12) + j) * 4 + d];
        out[((((size_t)b << 12) + j) << 2) + d] = segl + tanh_fast(s);
    }
}

// ---------------- launcher ----------------------------------------------------------------
extern "C" void kernel_launch(void* const* d_in, const int* in_sizes, int n_in,
                              void* d_out, int out_size, void* d_ws, size_t ws_size,
                              hipStream_t stream)
{
    (void)in_sizes; (void)n_in; (void)out_size; (void)ws_size;
    const float* ts    = (const float*)d_in[0];
    const int*   edges = (const int*)d_in[1];
    const float* Wc1   = (const float*)d_in[2];
    const float* bc1   = (const float*)d_in[3];
    const float* Wc2   = (const float*)d_in[4];
    const float* bc2   = (const float*)d_in[5];
    const float* Wg1   = (const float*)d_in[6];
    const float* bg    = (const float*)d_in[7];
    const float* Wd    = (const float*)d_in[8];
    const float* bd    = (const float*)d_in[9];
    const float* Wo    = (const float*)d_in[10];
    const float* bo    = (const float*)d_in[11];
    float* out = (float*)d_out;

    char* ws = (char*)d_ws;
    ushort_t* condT   = (ushort_t*)(ws);                              // 2 MiB
    ushort_t* condB   = (ushort_t*)(ws + (size_t)(2 << 20));          // 2 MiB
    float*    agg0    = (float*)(ws + (size_t)(4 << 20));             // 4 MiB
    float*    agg1    = (float*)(ws + (size_t)(8 << 20));             // 4 MiB
    float*    agg2    = (float*)(ws + (size_t)(12 << 20));            // 4 MiB
    float*    agg3    = (float*)(ws + (size_t)(16 << 20));            // 4 MiB
    int*      degI    = (int*)(ws + (size_t)(20 << 20));              // 16 KiB
    uint_t*   colbits = (uint_t*)(ws + (size_t)(20 << 20) + 16384);   // 512 B
    unsigned char* diagB = (unsigned char*)(ws + (size_t)(20 << 20) + 16896); // 4 KiB
    ushort_t* WgT_ws  = (ushort_t*)(ws + (size_t)(20 << 20) + 20992); // 8 KiB
    ushort_t* WdT_ws  = (ushort_t*)(ws + (size_t)(20 << 20) + 29184); // 16 KiB
    ushort_t* Wc2T_ws = (ushort_t*)(ws + (size_t)(20 << 20) + 45568); // 12 KiB
    uint_t*   bits    = (uint_t*)(ws + (size_t)(21 << 20));           // 2 MiB packed adjacency

    k0_prep<<<4, 256, 0, stream>>>(Wc2, Wg1, Wd, Wc2T_ws, WgT_ws, WdT_ws, colbits);
    k2_bits<<<512, 1024, 0, stream>>>((const int4*)edges, bits, degI, colbits, diagB);
    k1_cond<<<dim3(64, 4), 256, 0, stream>>>(ts, Wc1, bc1, Wc2T_ws, bc2, condT, condB);
    k3_gemm<<<512, 1024, 0, stream>>>(bits, condT, agg0, agg1, agg2, agg3);
    k4_mlp<<<dim3(64, 4), 256, 0, stream>>>(ts, condB, agg0, agg1, agg2, agg3,
                                            degI, colbits, diagB,
                                            WgT_ws, bg, WdT_ws, bd, Wo, bo, out);
}

// Round 4
// 172.817 us; speedup vs baseline: 1.0979x; 1.0979x over previous
//
#include <hip/hip_runtime.h>
#include <math.h>

typedef unsigned short ushort_t;
typedef unsigned int uint_t;
typedef unsigned long long u64_t;
typedef __attribute__((ext_vector_type(8))) __bf16 bf16x8;
typedef __attribute__((ext_vector_type(4))) float f32x4;

#define NN 4096
#define TT 5
#define F1 32
#define F2 64

// round-to-nearest-even fp32 -> bf16 bits
__device__ __forceinline__ ushort_t f2bf(float x) {
    union { float f; uint_t u; } v; v.f = x;
    uint_t r = (v.u + 0x7FFFu + ((v.u >> 16) & 1u)) >> 16;
    return (ushort_t)r;
}
__device__ __forceinline__ uint_t pk2(float a, float b) {
    return (uint_t)f2bf(a) | ((uint_t)f2bf(b) << 16);
}
// fast tanh: (e^2x - 1)/(e^2x + 1), clamped; err ~1e-6 (irrelevant vs bf16 noise)
__device__ __forceinline__ float tanh_fast(float x) {
    const float xc = fminf(fmaxf(x, -10.f), 10.f);
    const float e = __expf(2.f * xc);
    return (e - 1.f) * __builtin_amdgcn_rcpf(e + 1.f);
}

// ---------------- K2: edges (64 MiB) -> bits (2 MiB) + deg + colbits + diag --------------
// 512 blocks x 1024 thr, 2 blocks/CU, one round. Thread t reads 128 B contiguous
// (8 x int4 from one base, imm offsets). Block bid owns exactly rows [bid*8, bid*8+8):
// deg = wave shfl-reduce + PLAIN store (no atomics, no zeroing); colbits LDS-reduced
// (8-way) then one global atomicOr per word; diag = 8 byte stores per block.
__global__ __launch_bounds__(1024, 8) void k2_bits(
    const int4* __restrict__ edges4, uint_t* __restrict__ bits,
    int* __restrict__ degI, uint_t* __restrict__ colbits, unsigned char* __restrict__ diagB)
{
    const int t = threadIdx.x;
    const int bid = blockIdx.x;
    const uint_t W = (uint_t)bid * 1024u + (uint_t)t;   // word id; row=W>>7, word=W&127
    __shared__ uint_t colsh[128];
    __shared__ int sdeg[16];

    const int4* ep = edges4 + (size_t)W * 8;
    int4 v[8];
    #pragma unroll
    for (int c = 0; c < 8; ++c) v[c] = ep[c];

    if (t < 128) colsh[t] = 0;

    uint_t bw = 0;
    #pragma unroll
    for (int c = 0; c < 8; ++c) {
        const uint_t nib = (v[c].x != 0 ? 1u : 0u) | (v[c].y != 0 ? 2u : 0u) |
                           (v[c].z != 0 ? 4u : 0u) | (v[c].w != 0 ? 8u : 0u);
        bw |= nib << (c * 4);
    }
    bits[W] = bw;

    const int row = (int)(W >> 7);
    if ((t & 127) == (row >> 5))
        diagB[row] = (unsigned char)((bw >> (row & 31)) & 1u);

    // each wave lies entirely within one row (64 of its 128 words)
    int s = __popc(bw);
    #pragma unroll
    for (int off = 32; off >= 1; off >>= 1) s += __shfl_down(s, off);
    const int w = t >> 6, l = t & 63;
    if (l == 0) sdeg[w] = s;
    __syncthreads();                    // colsh zeroed + sdeg visible
    atomicOr(&colsh[t & 127], bw);      // 8-way LDS contention per word
    __syncthreads();
    if (t < 128) atomicOr(&colbits[t], colsh[t]);
    if (t < 8) degI[bid * 8 + t] = sdeg[2 * t] + sdeg[2 * t + 1];
}

// ---------------- K1: conv1 (VALU) + conv2 (MFMA) -> condT (col-major) + condB (row-major)
#define H1S 104
#define CBS 80
__global__ __launch_bounds__(256) void k1_cond(
    const float* __restrict__ ts, const float* __restrict__ Wc1, const float* __restrict__ bc1,
    const float* __restrict__ Wc2, const float* __restrict__ bc2,
    ushort_t* __restrict__ condT, ushort_t* __restrict__ condB)
{
    const int b = blockIdx.y;
    const int j0 = blockIdx.x * 64;
    const int t = threadIdx.x;

    __shared__ float sWc1[384];
    __shared__ float sbc1[F1];
    __shared__ float sbc2[F2];
    __shared__ ushort_t sWc2T[64 * H1S];
    __shared__ ushort_t h1B[64 * H1S];
    __shared__ ushort_t scb[64 * CBS];

    for (int i = t; i < 384; i += 256) sWc1[i] = Wc1[i];
    if (t < F1) sbc1[t] = bc1[t];
    if (t < F2) sbc2[t] = bc2[t];
    for (int i = t; i < 96 * 64; i += 256) {
        const int e = i >> 6, f = i & 63;
        sWc2T[f * H1S + e] = f2bf(Wc2[i]);
    }
    __syncthreads();

    {   // phase A: h1 = relu(conv1)
        const int n = t & 63, f10 = (t >> 6) * 8;
        const int j = j0 + n;
        float4 x[5];
        #pragma unroll
        for (int tt = 0; tt < 5; ++tt)
            x[tt] = *(const float4*)(ts + ((((size_t)b * TT + tt) << 12) + j) * 4);
        #pragma unroll
        for (int tt0 = 0; tt0 < 3; ++tt0) {
            #pragma unroll
            for (int ff = 0; ff < 8; ++ff) {
                const int f1 = f10 + ff;
                float a = sbc1[f1];
                #pragma unroll
                for (int dt = 0; dt < 3; ++dt) {
                    const float4 xx = x[tt0 + dt];
                    a += xx.x * sWc1[(dt * 4 + 0) * F1 + f1];
                    a += xx.y * sWc1[(dt * 4 + 1) * F1 + f1];
                    a += xx.z * sWc1[(dt * 4 + 2) * F1 + f1];
                    a += xx.w * sWc1[(dt * 4 + 3) * F1 + f1];
                }
                h1B[n * H1S + tt0 * 32 + f1] = f2bf(fmaxf(a, 0.f));
            }
        }
    }
    __syncthreads();

    {   // phase B: cond = h1 @ Wc2 + bc2 via MFMA
        const int w = t >> 6, l = t & 63;
        const int m0 = w * 16, kseg = (l >> 4) * 8;
        f32x4 acc[4] = {};
        #pragma unroll
        for (int ks = 0; ks < 3; ++ks) {
            const bf16x8 av = *(const bf16x8*)&h1B[(m0 + (l & 15)) * H1S + ks * 32 + kseg];
            #pragma unroll
            for (int ct = 0; ct < 4; ++ct) {
                const bf16x8 bv = *(const bf16x8*)&sWc2T[(ct * 16 + (l & 15)) * H1S + ks * 32 + kseg];
                acc[ct] = __builtin_amdgcn_mfma_f32_16x16x32_bf16(av, bv, acc[ct], 0, 0, 0);
            }
        }
        #pragma unroll
        for (int ct = 0; ct < 4; ++ct)
            #pragma unroll
            for (int i = 0; i < 4; ++i) {
                const int row = m0 + (l >> 4) * 4 + i;
                const int col = ct * 16 + (l & 15);
                scb[col * CBS + row] = f2bf(acc[ct][i] + sbc2[col]);
            }
    }
    __syncthreads();
    {   // condT writeback (col-major [b][f][j])
        const int f2 = t >> 2, seg = t & 3;
        ushort_t* dst = condT + (((size_t)b * 64 + f2) << 12) + j0 + seg * 16;
        *(uint4*)dst = *(const uint4*)&scb[f2 * CBS + seg * 16];
        *(uint4*)(dst + 8) = *(const uint4*)&scb[f2 * CBS + seg * 16 + 8];
    }
    {   // condB writeback (row-major [b][j][f]) — transpose read from scb
        const int r = t >> 2, q = t & 3;
        uint_t u[8];
        #pragma unroll
        for (int k = 0; k < 8; ++k)
            u[k] = (uint_t)scb[(q * 16 + 2 * k) * CBS + r] |
                   ((uint_t)scb[(q * 16 + 2 * k + 1) * CBS + r] << 16);
        ushort_t* dstB = condB + ((((size_t)b << 12) + j0 + r) << 6) + q * 16;
        *(uint4*)dstB = make_uint4(u[0], u[1], u[2], u[3]);
        *(uint4*)(dstB + 8) = make_uint4(u[4], u[5], u[6], u[7]);
    }
}

// ---------------- K3: bit-staged adjacency GEMM (pure) -----------------------------------
// grid 512 = 128 row-stripes(32r) x 4 k-splits(1024); 1024 thr (16 waves), 2 blocks/CU.
// A-tile staging: 1 uint of bits per thread (4 KB/block from L2), expanded in-register to
// bf16 {0,1} into the swizzled LDS layout the MFMA loop reads. Single barrier.
__global__ __launch_bounds__(1024, 8) void k3_gemm(
    const uint_t* __restrict__ bits, const ushort_t* __restrict__ condT,
    float* __restrict__ agg0, float* __restrict__ agg1,
    float* __restrict__ agg2, float* __restrict__ agg3)
{
    const int t = threadIdx.x;
    const int stripe = blockIdx.x >> 2, ks4 = blockIdx.x & 3;
    const int j0 = stripe * 32, kb = ks4 * 1024;

    __shared__ __align__(16) ushort_t abuf[8][4096];   // 64 KB: 8 chunks x (32r x 128k)

    // staging map: t = rh*512 + wq*16 + rl  (16 distinct rl per wave -> conflict-free writes)
    const int rl = t & 15, wq = (t >> 4) & 31, rh = t >> 9;
    const uint_t bw = bits[(size_t)(j0 + rh * 16 + rl) * 128 + (size_t)(kb >> 5) + (size_t)wq];
    {
        // word wq covers chunk wq>>2, k-seg wq&3; storage index matches the aoff read:
        // addr(rh,rl,ks,o,w) = rh*2048 + ks*512 + o*128 + ((rl*8)^(o<<4)) + w
        ushort_t* dst = &abuf[wq >> 2][rh * 2048 + (wq & 3) * 512];
        #pragma unroll
        for (int o = 0; o < 4; ++o) {
            const uint_t oct = bw >> (o * 8);
            uint4 wv;
            wv.x = ((oct & 1u)   ? 0x3F80u : 0u) | ((oct & 2u)   ? 0x3F800000u : 0u);
            wv.y = ((oct & 4u)   ? 0x3F80u : 0u) | ((oct & 8u)   ? 0x3F800000u : 0u);
            wv.z = ((oct & 16u)  ? 0x3F80u : 0u) | ((oct & 32u)  ? 0x3F800000u : 0u);
            wv.w = ((oct & 64u)  ? 0x3F80u : 0u) | ((oct & 128u) ? 0x3F800000u : 0u);
            *(uint4*)(dst + o * 128 + ((rl * 8) ^ (o << 4))) = wv;
        }
    }
    __syncthreads();

    const int w = t >> 6, l = t & 63;
    const int aoff = (l * 8) ^ ((l >> 4) << 4);
    const ushort_t* bp = condT + (size_t)(w * 16 + (l & 15)) * NN + kb + (l >> 4) * 8;

    f32x4 acc0 = {0.f, 0.f, 0.f, 0.f};
    f32x4 acc1 = {0.f, 0.f, 0.f, 0.f};

    #pragma unroll
    for (int ch = 0; ch < 8; ++ch) {
        const ushort_t* ab = &abuf[ch][0];
        const ushort_t* bpi = bp + ch * 128;
        #pragma unroll
        for (int ks = 0; ks < 4; ++ks) {
            const bf16x8 bfv = *(const bf16x8*)(bpi + ks * 32);
            const bf16x8 a0 = *(const bf16x8*)(ab + ks * 512 + aoff);
            const bf16x8 a1 = *(const bf16x8*)(ab + 2048 + ks * 512 + aoff);
            acc0 = __builtin_amdgcn_mfma_f32_16x16x32_bf16(a0, bfv, acc0, 0, 0, 0);
            acc1 = __builtin_amdgcn_mfma_f32_16x16x32_bf16(a1, bfv, acc1, 0, 0, 0);
        }
    }

    // epilogue: plain stores to this split's slab
    {
        float* aggS = (ks4 == 0) ? agg0 : (ks4 == 1) ? agg1 : (ks4 == 2) ? agg2 : agg3;
        const int col = w * 16 + (l & 15);
        float* dst = aggS + ((size_t)(col >> 6) * NN << 6) + (col & 63);
        #pragma unroll
        for (int i = 0; i < 4; ++i) {
            const int ja = j0 + (l >> 4) * 4 + i;
            dst[(size_t)ja << 6] = acc0[i];
            dst[(size_t)(ja + 16) << 6] = acc1[i];
        }
    }
}

// ---------------- K4: MLP epilogue on MFMA; 64 rows/block, grid (64,4) -------------------
#define WGS 88
#define WDS 136
#define HS  69
__global__ __launch_bounds__(256) void k4_mlp(
    const float* __restrict__ ts, const ushort_t* __restrict__ condB,
    const float* __restrict__ agg0, const float* __restrict__ agg1,
    const float* __restrict__ agg2, const float* __restrict__ agg3,
    const int* __restrict__ degI, const uint_t* __restrict__ colbits,
    const unsigned char* __restrict__ diagB,
    const float* __restrict__ Wg1, const float* __restrict__ bg,
    const float* __restrict__ Wd, const float* __restrict__ bd,
    const float* __restrict__ Wo, const float* __restrict__ bo,
    float* __restrict__ out)
{
    const int b = blockIdx.y;
    const int j0 = blockIdx.x * 64;
    const int t = threadIdx.x;

    __shared__ ushort_t sWg1T[64 * WGS];
    __shared__ ushort_t sWdT[64 * WDS];
    __shared__ ushort_t aggB[64 * WGS];
    __shared__ ushort_t catB[64 * WDS];
    __shared__ float sH[64 * HS];
    __shared__ float sWo[256];
    __shared__ float sbg[64], sbd[64], sbo[4], sAlive[64];

    for (int i = t; i < 4096; i += 256) {
        const int in = i >> 6, o = i & 63;
        sWg1T[o * WGS + in] = f2bf(Wg1[i]);
    }
    for (int i = t; i < 8192; i += 256) {
        const int in = i >> 6, o = i & 63;
        sWdT[o * WDS + in] = f2bf(Wd[i]);
    }
    if (t < 256) sWo[t] = Wo[t];
    if (t < 64) { sbg[t] = bg[t]; sbd[t] = bd[t]; }
    if (t < 4) sbo[t] = bo[t];
    if (t < 64) {
        const int j = j0 + t;
        sAlive[t] = (float)((colbits[j >> 5] >> (j & 31)) & 1u);
    }
    {   // phase 0: aggN = (sum slabs - diag*cond_bf16)/deg -> bf16; catB = cond_bf16 copy
        const int r = t >> 2, fs = t & 3;
        const int j = j0 + r;
        const float dv = (float)degI[j];
        const float inv = 1.f / (dv > 0.f ? dv : 1.f);
        const float dgf = (float)diagB[j];
        const size_t base = (((size_t)b << 12) + j) << 6;
        const uint4 c0 = *(const uint4*)(condB + base + fs * 16);
        const uint4 c1 = *(const uint4*)(condB + base + fs * 16 + 8);
        *(uint4*)&catB[r * WDS + fs * 16] = c0;
        *(uint4*)&catB[r * WDS + fs * 16 + 8] = c1;
        #pragma unroll
        for (int q = 0; q < 4; ++q) {
            uint_t wlo, whi;
            if (q == 0)      { wlo = c0.x; whi = c0.y; }
            else if (q == 1) { wlo = c0.z; whi = c0.w; }
            else if (q == 2) { wlo = c1.x; whi = c1.y; }
            else             { wlo = c1.z; whi = c1.w; }
            const int f = fs * 16 + q * 4;
            const float4 a0 = *(const float4*)(agg0 + base + f);
            const float4 a1 = *(const float4*)(agg1 + base + f);
            const float4 a2 = *(const float4*)(agg2 + base + f);
            const float4 a3 = *(const float4*)(agg3 + base + f);
            const float cv0 = __uint_as_float(wlo << 16);
            const float cv1 = __uint_as_float(wlo & 0xFFFF0000u);
            const float cv2 = __uint_as_float(whi << 16);
            const float cv3 = __uint_as_float(whi & 0xFFFF0000u);
            const float n0 = (a0.x + a1.x + a2.x + a3.x - dgf * cv0) * inv;
            const float n1 = (a0.y + a1.y + a2.y + a3.y - dgf * cv1) * inv;
            const float n2 = (a0.z + a1.z + a2.z + a3.z - dgf * cv2) * inv;
            const float n3 = (a0.w + a1.w + a2.w + a3.w - dgf * cv3) * inv;
            *(uint2*)&aggB[r * WGS + f] = make_uint2(pk2(n0, n1), pk2(n2, n3));
        }
    }
    __syncthreads();

    const int w = t >> 6, l = t & 63;
    const int m0 = w * 16, kseg = (l >> 4) * 8;

    {   // phase G
        f32x4 acc[4] = {};
        #pragma unroll
        for (int ks = 0; ks < 2; ++ks) {
            const bf16x8 av = *(const bf16x8*)&aggB[(m0 + (l & 15)) * WGS + ks * 32 + kseg];
            #pragma unroll
            for (int ct = 0; ct < 4; ++ct) {
                const bf16x8 bv = *(const bf16x8*)&sWg1T[(ct * 16 + (l & 15)) * WGS + ks * 32 + kseg];
                acc[ct] = __builtin_amdgcn_mfma_f32_16x16x32_bf16(av, bv, acc[ct], 0, 0, 0);
            }
        }
        #pragma unroll
        for (int ct = 0; ct < 4; ++ct)
            #pragma unroll
            for (int i = 0; i < 4; ++i) {
                const int row = m0 + (l >> 4) * 4 + i;
                const int col = ct * 16 + (l & 15);
                const float g = tanh_fast(acc[ct][i] + sbg[col]) * sAlive[row];
                catB[row * WDS + 64 + col] = f2bf(g);
            }
    }
    __syncthreads();
    {   // phase H
        f32x4 acc[4] = {};
        #pragma unroll
        for (int ks = 0; ks < 4; ++ks) {
            const bf16x8 av = *(const bf16x8*)&catB[(m0 + (l & 15)) * WDS + ks * 32 + kseg];
            #pragma unroll
            for (int ct = 0; ct < 4; ++ct) {
                const bf16x8 bv = *(const bf16x8*)&sWdT[(ct * 16 + (l & 15)) * WDS + ks * 32 + kseg];
                acc[ct] = __builtin_amdgcn_mfma_f32_16x16x32_bf16(av, bv, acc[ct], 0, 0, 0);
            }
        }
        #pragma unroll
        for (int ct = 0; ct < 4; ++ct)
            #pragma unroll
            for (int i = 0; i < 4; ++i) {
                const int row = m0 + (l >> 4) * 4 + i;
                const int col = ct * 16 + (l & 15);
                sH[row * HS + col] = fmaxf(acc[ct][i] + sbd[col], 0.f);
            }
    }
    __syncthreads();
    {   // phase O
        const int r = t >> 2, d = t & 3;
        const int j = j0 + r;
        float s = sbo[d];
        #pragma unroll 8
        for (int f = 0; f < 64; ++f) s += sH[r * HS + f] * sWo[f * 4 + d];
        const float segl = ts[((((size_t)b * TT + 4) << 12) + j) * 4 + d];
        out[((((size_t)b << 12) + j) << 2) + d] = segl + tanh_fast(s);
    }
}

// ---------------- launcher ----------------------------------------------------------------
extern "C" void kernel_launch(void* const* d_in, const int* in_sizes, int n_in,
                              void* d_out, int out_size, void* d_ws, size_t ws_size,
                              hipStream_t stream)
{
    (void)in_sizes; (void)n_in; (void)out_size; (void)ws_size;
    const float* ts    = (const float*)d_in[0];
    const int*   edges = (const int*)d_in[1];
    const float* Wc1   = (const float*)d_in[2];
    const float* bc1   = (const float*)d_in[3];
    const float* Wc2   = (const float*)d_in[4];
    const float* bc2   = (const float*)d_in[5];
    const float* Wg1   = (const float*)d_in[6];
    const float* bg    = (const float*)d_in[7];
    const float* Wd    = (const float*)d_in[8];
    const float* bd    = (const float*)d_in[9];
    const float* Wo    = (const float*)d_in[10];
    const float* bo    = (const float*)d_in[11];
    float* out = (float*)d_out;

    char* ws = (char*)d_ws;
    ushort_t* condT   = (ushort_t*)(ws);                              // 2 MiB
    ushort_t* condB   = (ushort_t*)(ws + (size_t)(2 << 20));          // 2 MiB
    float*    agg0    = (float*)(ws + (size_t)(4 << 20));             // 4 MiB
    float*    agg1    = (float*)(ws + (size_t)(8 << 20));             // 4 MiB
    float*    agg2    = (float*)(ws + (size_t)(12 << 20));            // 4 MiB
    float*    agg3    = (float*)(ws + (size_t)(16 << 20));            // 4 MiB
    int*      degI    = (int*)(ws + (size_t)(20 << 20));              // 16 KiB
    uint_t*   colbits = (uint_t*)(ws + (size_t)(20 << 20) + 16384);   // 512 B
    unsigned char* diagB = (unsigned char*)(ws + (size_t)(20 << 20) + 16896); // 4 KiB
    uint_t*   bits    = (uint_t*)(ws + (size_t)(21 << 20));           // 2 MiB packed adjacency

    hipMemsetAsync(colbits, 0, 512, stream);
    k2_bits<<<512, 1024, 0, stream>>>((const int4*)edges, bits, degI, colbits, diagB);
    k1_cond<<<dim3(64, 4), 256, 0, stream>>>(ts, Wc1, bc1, Wc2, bc2, condT, condB);
    k3_gemm<<<512, 1024, 0, stream>>>(bits, condT, agg0, agg1, agg2, agg3);
    k4_mlp<<<dim3(64, 4), 256, 0, stream>>>(ts, condB, agg0, agg1, agg2, agg3,
                                            degI, colbits, diagB,
                                            Wg1, bg, Wd, bd, Wo, bo, out);
}

// Round 5
// 161.459 us; speedup vs baseline: 1.1751x; 1.0703x over previous
//
#include <hip/hip_runtime.h>
#include <math.h>

typedef unsigned short ushort_t;
typedef unsigned int uint_t;
typedef unsigned long long u64_t;
typedef __attribute__((ext_vector_type(8))) __bf16 bf16x8;
typedef __attribute__((ext_vector_type(4))) float f32x4;

#define NN 4096
#define TT 5
#define F1 32
#define F2 64

// round-to-nearest-even fp32 -> bf16 bits
__device__ __forceinline__ ushort_t f2bf(float x) {
    union { float f; uint_t u; } v; v.f = x;
    uint_t r = (v.u + 0x7FFFu + ((v.u >> 16) & 1u)) >> 16;
    return (ushort_t)r;
}
__device__ __forceinline__ uint_t pk2(float a, float b) {
    return (uint_t)f2bf(a) | ((uint_t)f2bf(b) << 16);
}
// fast tanh: (e^2x - 1)/(e^2x + 1), clamped; err ~1e-6 (irrelevant vs bf16 noise)
__device__ __forceinline__ float tanh_fast(float x) {
    const float xc = fminf(fmaxf(x, -10.f), 10.f);
    const float e = __expf(2.f * xc);
    return (e - 1.f) * __builtin_amdgcn_rcpf(e + 1.f);
}

// ---------------- K2: edges (64 MiB) -> bits (2 MiB) + deg + colbits + diag --------------
// 512 blocks x 1024 thr, 2 blocks/CU. Thread t reads 128 B contiguous (8 x int4).
// Block bid owns exactly rows [bid*8, bid*8+8): deg = wave shfl-reduce + PLAIN store;
// colbits LDS-reduced (8-way) then one global atomicOr per word; diag = 8 byte stores.
__global__ __launch_bounds__(1024, 8) void k2_bits(
    const int4* __restrict__ edges4, uint_t* __restrict__ bits,
    int* __restrict__ degI, uint_t* __restrict__ colbits, unsigned char* __restrict__ diagB)
{
    const int t = threadIdx.x;
    const int bid = blockIdx.x;
    const uint_t W = (uint_t)bid * 1024u + (uint_t)t;   // word id; row=W>>7, word=W&127
    __shared__ uint_t colsh[128];
    __shared__ int sdeg[16];

    const int4* ep = edges4 + (size_t)W * 8;
    int4 v[8];
    #pragma unroll
    for (int c = 0; c < 8; ++c) v[c] = ep[c];

    if (t < 128) colsh[t] = 0;

    uint_t bw = 0;
    #pragma unroll
    for (int c = 0; c < 8; ++c) {
        const uint_t nib = (v[c].x != 0 ? 1u : 0u) | (v[c].y != 0 ? 2u : 0u) |
                           (v[c].z != 0 ? 4u : 0u) | (v[c].w != 0 ? 8u : 0u);
        bw |= nib << (c * 4);
    }
    bits[W] = bw;

    const int row = (int)(W >> 7);
    if ((t & 127) == (row >> 5))
        diagB[row] = (unsigned char)((bw >> (row & 31)) & 1u);

    // each wave lies entirely within one row (64 of its 128 words)
    int s = __popc(bw);
    #pragma unroll
    for (int off = 32; off >= 1; off >>= 1) s += __shfl_down(s, off);
    const int w = t >> 6, l = t & 63;
    if (l == 0) sdeg[w] = s;
    __syncthreads();                    // colsh zeroed + sdeg visible
    atomicOr(&colsh[t & 127], bw);      // 8-way LDS contention per word
    __syncthreads();
    if (t < 128) atomicOr(&colbits[t], colsh[t]);
    if (t < 8) degI[bid * 8 + t] = sdeg[2 * t] + sdeg[2 * t + 1];
}

// ---------------- K1: conv1 (VALU) + conv2 (MFMA) -> condP (k3 layout) + condB (row-major)
// condP layout: [J][fg][jj], J = j>>5 (128 blocks of 32 nodes), fg = b*64+f (256),
// jj = j&31. One wave-load in k3 then covers exactly 1 KB contiguous.
#define H1S 104
#define CBS 80
__global__ __launch_bounds__(256) void k1_cond(
    const float* __restrict__ ts, const float* __restrict__ Wc1, const float* __restrict__ bc1,
    const float* __restrict__ Wc2, const float* __restrict__ bc2,
    ushort_t* __restrict__ condP, ushort_t* __restrict__ condB)
{
    const int b = blockIdx.y;
    const int j0 = blockIdx.x * 64;
    const int t = threadIdx.x;

    __shared__ float sWc1[384];
    __shared__ float sbc1[F1];
    __shared__ float sbc2[F2];
    __shared__ ushort_t sWc2T[64 * H1S];
    __shared__ ushort_t h1B[64 * H1S];
    __shared__ ushort_t scb[64 * CBS];

    for (int i = t; i < 384; i += 256) sWc1[i] = Wc1[i];
    if (t < F1) sbc1[t] = bc1[t];
    if (t < F2) sbc2[t] = bc2[t];
    for (int i = t; i < 96 * 64; i += 256) {
        const int e = i >> 6, f = i & 63;
        sWc2T[f * H1S + e] = f2bf(Wc2[i]);
    }
    __syncthreads();

    {   // phase A: h1 = relu(conv1)
        const int n = t & 63, f10 = (t >> 6) * 8;
        const int j = j0 + n;
        float4 x[5];
        #pragma unroll
        for (int tt = 0; tt < 5; ++tt)
            x[tt] = *(const float4*)(ts + ((((size_t)b * TT + tt) << 12) + j) * 4);
        #pragma unroll
        for (int tt0 = 0; tt0 < 3; ++tt0) {
            #pragma unroll
            for (int ff = 0; ff < 8; ++ff) {
                const int f1 = f10 + ff;
                float a = sbc1[f1];
                #pragma unroll
                for (int dt = 0; dt < 3; ++dt) {
                    const float4 xx = x[tt0 + dt];
                    a += xx.x * sWc1[(dt * 4 + 0) * F1 + f1];
                    a += xx.y * sWc1[(dt * 4 + 1) * F1 + f1];
                    a += xx.z * sWc1[(dt * 4 + 2) * F1 + f1];
                    a += xx.w * sWc1[(dt * 4 + 3) * F1 + f1];
                }
                h1B[n * H1S + tt0 * 32 + f1] = f2bf(fmaxf(a, 0.f));
            }
        }
    }
    __syncthreads();

    {   // phase B: cond = h1 @ Wc2 + bc2 via MFMA
        const int w = t >> 6, l = t & 63;
        const int m0 = w * 16, kseg = (l >> 4) * 8;
        f32x4 acc[4] = {};
        #pragma unroll
        for (int ks = 0; ks < 3; ++ks) {
            const bf16x8 av = *(const bf16x8*)&h1B[(m0 + (l & 15)) * H1S + ks * 32 + kseg];
            #pragma unroll
            for (int ct = 0; ct < 4; ++ct) {
                const bf16x8 bv = *(const bf16x8*)&sWc2T[(ct * 16 + (l & 15)) * H1S + ks * 32 + kseg];
                acc[ct] = __builtin_amdgcn_mfma_f32_16x16x32_bf16(av, bv, acc[ct], 0, 0, 0);
            }
        }
        #pragma unroll
        for (int ct = 0; ct < 4; ++ct)
            #pragma unroll
            for (int i = 0; i < 4; ++i) {
                const int row = m0 + (l >> 4) * 4 + i;
                const int col = ct * 16 + (l & 15);
                scb[col * CBS + row] = f2bf(acc[ct][i] + sbc2[col]);
            }
    }
    __syncthreads();
    {   // condP writeback: element (fg=b*64+f, j) -> condP[(j>>5)*8192 + fg*32 + (j&31)]
        const int f2 = t >> 2, seg = t & 3;
        const int J = (j0 >> 5) + (seg >> 1);
        ushort_t* dst = condP + (size_t)J * 8192 + ((size_t)b * 64 + f2) * 32 + (seg & 1) * 16;
        *(uint4*)dst = *(const uint4*)&scb[f2 * CBS + seg * 16];
        *(uint4*)(dst + 8) = *(const uint4*)&scb[f2 * CBS + seg * 16 + 8];
    }
    {   // condB writeback (row-major [b][j][f]) — transpose read from scb
        const int r = t >> 2, q = t & 3;
        uint_t u[8];
        #pragma unroll
        for (int k = 0; k < 8; ++k)
            u[k] = (uint_t)scb[(q * 16 + 2 * k) * CBS + r] |
                   ((uint_t)scb[(q * 16 + 2 * k + 1) * CBS + r] << 16);
        ushort_t* dstB = condB + ((((size_t)b << 12) + j0 + r) << 6) + q * 16;
        *(uint4*)dstB = make_uint4(u[0], u[1], u[2], u[3]);
        *(uint4*)(dstB + 8) = make_uint4(u[4], u[5], u[6], u[7]);
    }
}

// ---------------- K3: bit-staged adjacency GEMM, coalesced B -----------------------------
// grid 512 = 128 row-stripes(32r) x 4 k-splits(1024); 1024 thr (16 waves), 2 blocks/CU.
// A: 1 uint of bits per thread (4 KB/block), expanded in-register to bf16 {0,1} into the
// swizzled LDS layout. B: condP layout -> every wave b128 load is 1 KB dense (16 fg x 64 B),
// replacing the old 8 KB-stride 64-line gathers that dominated k3's runtime.
__global__ __launch_bounds__(1024, 8) void k3_gemm(
    const uint_t* __restrict__ bits, const ushort_t* __restrict__ condP,
    float* __restrict__ agg0, float* __restrict__ agg1,
    float* __restrict__ agg2, float* __restrict__ agg3)
{
    const int t = threadIdx.x;
    const int stripe = blockIdx.x >> 2, ks4 = blockIdx.x & 3;
    const int j0 = stripe * 32, kb = ks4 * 1024;

    __shared__ __align__(16) ushort_t abuf[8][4096];   // 64 KB: 8 chunks x (32r x 128k)

    // staging map: t = rh*512 + wq*16 + rl  (16 distinct rl per wave -> conflict-free writes)
    const int rl = t & 15, wq = (t >> 4) & 31, rh = t >> 9;
    const uint_t bw = bits[(size_t)(j0 + rh * 16 + rl) * 128 + (size_t)(kb >> 5) + (size_t)wq];
    {
        // word wq covers chunk wq>>2, k-seg wq&3; storage index matches the aoff read:
        // addr(rh,rl,ks,o,w) = rh*2048 + ks*512 + o*128 + ((rl*8)^(o<<4)) + w
        ushort_t* dst = &abuf[wq >> 2][rh * 2048 + (wq & 3) * 512];
        #pragma unroll
        for (int o = 0; o < 4; ++o) {
            const uint_t oct = bw >> (o * 8);
            uint4 wv;
            wv.x = ((oct & 1u)   ? 0x3F80u : 0u) | ((oct & 2u)   ? 0x3F800000u : 0u);
            wv.y = ((oct & 4u)   ? 0x3F80u : 0u) | ((oct & 8u)   ? 0x3F800000u : 0u);
            wv.z = ((oct & 16u)  ? 0x3F80u : 0u) | ((oct & 32u)  ? 0x3F800000u : 0u);
            wv.w = ((oct & 64u)  ? 0x3F80u : 0u) | ((oct & 128u) ? 0x3F800000u : 0u);
            *(uint4*)(dst + o * 128 + ((rl * 8) ^ (o << 4))) = wv;
        }
    }
    __syncthreads();

    const int w = t >> 6, l = t & 63;
    const int aoff = (l * 8) ^ ((l >> 4) << 4);
    // B base: fg = w*16 + (l&15), jj = (l>>4)*8; step (ch*4+ks) advances J by 1 (8192 hw)
    const ushort_t* bp = condP + (size_t)(kb >> 5) * 8192 + (size_t)w * 512
                       + (l & 15) * 32 + (l >> 4) * 8;

    f32x4 acc0 = {0.f, 0.f, 0.f, 0.f};
    f32x4 acc1 = {0.f, 0.f, 0.f, 0.f};

    #pragma unroll
    for (int ch = 0; ch < 8; ++ch) {
        const ushort_t* ab = &abuf[ch][0];
        #pragma unroll
        for (int ks = 0; ks < 4; ++ks) {
            const bf16x8 bfv = *(const bf16x8*)(bp + (size_t)(ch * 4 + ks) * 8192);
            const bf16x8 a0 = *(const bf16x8*)(ab + ks * 512 + aoff);
            const bf16x8 a1 = *(const bf16x8*)(ab + 2048 + ks * 512 + aoff);
            acc0 = __builtin_amdgcn_mfma_f32_16x16x32_bf16(a0, bfv, acc0, 0, 0, 0);
            acc1 = __builtin_amdgcn_mfma_f32_16x16x32_bf16(a1, bfv, acc1, 0, 0, 0);
        }
    }

    // epilogue: plain stores to this split's slab
    {
        float* aggS = (ks4 == 0) ? agg0 : (ks4 == 1) ? agg1 : (ks4 == 2) ? agg2 : agg3;
        const int col = w * 16 + (l & 15);
        float* dst = aggS + ((size_t)(col >> 6) * NN << 6) + (col & 63);
        #pragma unroll
        for (int i = 0; i < 4; ++i) {
            const int ja = j0 + (l >> 4) * 4 + i;
            dst[(size_t)ja << 6] = acc0[i];
            dst[(size_t)(ja + 16) << 6] = acc1[i];
        }
    }
}

// ---------------- K4: MLP epilogue on MFMA; 64 rows/block, grid (64,4) -------------------
#define WGS 88
#define WDS 136
#define HS  69
__global__ __launch_bounds__(256) void k4_mlp(
    const float* __restrict__ ts, const ushort_t* __restrict__ condB,
    const float* __restrict__ agg0, const float* __restrict__ agg1,
    const float* __restrict__ agg2, const float* __restrict__ agg3,
    const int* __restrict__ degI, const uint_t* __restrict__ colbits,
    const unsigned char* __restrict__ diagB,
    const float* __restrict__ Wg1, const float* __restrict__ bg,
    const float* __restrict__ Wd, const float* __restrict__ bd,
    const float* __restrict__ Wo, const float* __restrict__ bo,
    float* __restrict__ out)
{
    const int b = blockIdx.y;
    const int j0 = blockIdx.x * 64;
    const int t = threadIdx.x;

    __shared__ ushort_t sWg1T[64 * WGS];
    __shared__ ushort_t sWdT[64 * WDS];
    __shared__ ushort_t aggB[64 * WGS];
    __shared__ ushort_t catB[64 * WDS];
    __shared__ float sH[64 * HS];
    __shared__ float sWo[256];
    __shared__ float sbg[64], sbd[64], sbo[4], sAlive[64];

    for (int i = t; i < 4096; i += 256) {
        const int in = i >> 6, o = i & 63;
        sWg1T[o * WGS + in] = f2bf(Wg1[i]);
    }
    for (int i = t; i < 8192; i += 256) {
        const int in = i >> 6, o = i & 63;
        sWdT[o * WDS + in] = f2bf(Wd[i]);
    }
    if (t < 256) sWo[t] = Wo[t];
    if (t < 64) { sbg[t] = bg[t]; sbd[t] = bd[t]; }
    if (t < 4) sbo[t] = bo[t];
    if (t < 64) {
        const int j = j0 + t;
        sAlive[t] = (float)((colbits[j >> 5] >> (j & 31)) & 1u);
    }
    {   // phase 0: aggN = (sum slabs - diag*cond_bf16)/deg -> bf16; catB = cond_bf16 copy
        const int r = t >> 2, fs = t & 3;
        const int j = j0 + r;
        const float dv = (float)degI[j];
        const float inv = 1.f / (dv > 0.f ? dv : 1.f);
        const float dgf = (float)diagB[j];
        const size_t base = (((size_t)b << 12) + j) << 6;
        const uint4 c0 = *(const uint4*)(condB + base + fs * 16);
        const uint4 c1 = *(const uint4*)(condB + base + fs * 16 + 8);
        *(uint4*)&catB[r * WDS + fs * 16] = c0;
        *(uint4*)&catB[r * WDS + fs * 16 + 8] = c1;
        #pragma unroll
        for (int q = 0; q < 4; ++q) {
            uint_t wlo, whi;
            if (q == 0)      { wlo = c0.x; whi = c0.y; }
            else if (q == 1) { wlo = c0.z; whi = c0.w; }
            else if (q == 2) { wlo = c1.x; whi = c1.y; }
            else             { wlo = c1.z; whi = c1.w; }
            const int f = fs * 16 + q * 4;
            const float4 a0 = *(const float4*)(agg0 + base + f);
            const float4 a1 = *(const float4*)(agg1 + base + f);
            const float4 a2 = *(const float4*)(agg2 + base + f);
            const float4 a3 = *(const float4*)(agg3 + base + f);
            const float cv0 = __uint_as_float(wlo << 16);
            const float cv1 = __uint_as_float(wlo & 0xFFFF0000u);
            const float cv2 = __uint_as_float(whi << 16);
            const float cv3 = __uint_as_float(whi & 0xFFFF0000u);
            const float n0 = (a0.x + a1.x + a2.x + a3.x - dgf * cv0) * inv;
            const float n1 = (a0.y + a1.y + a2.y + a3.y - dgf * cv1) * inv;
            const float n2 = (a0.z + a1.z + a2.z + a3.z - dgf * cv2) * inv;
            const float n3 = (a0.w + a1.w + a2.w + a3.w - dgf * cv3) * inv;
            *(uint2*)&aggB[r * WGS + f] = make_uint2(pk2(n0, n1), pk2(n2, n3));
        }
    }
    __syncthreads();

    const int w = t >> 6, l = t & 63;
    const int m0 = w * 16, kseg = (l >> 4) * 8;

    {   // phase G
        f32x4 acc[4] = {};
        #pragma unroll
        for (int ks = 0; ks < 2; ++ks) {
            const bf16x8 av = *(const bf16x8*)&aggB[(m0 + (l & 15)) * WGS + ks * 32 + kseg];
            #pragma unroll
            for (int ct = 0; ct < 4; ++ct) {
                const bf16x8 bv = *(const bf16x8*)&sWg1T[(ct * 16 + (l & 15)) * WGS + ks * 32 + kseg];
                acc[ct] = __builtin_amdgcn_mfma_f32_16x16x32_bf16(av, bv, acc[ct], 0, 0, 0);
            }
        }
        #pragma unroll
        for (int ct = 0; ct < 4; ++ct)
            #pragma unroll
            for (int i = 0; i < 4; ++i) {
                const int row = m0 + (l >> 4) * 4 + i;
                const int col = ct * 16 + (l & 15);
                const float g = tanh_fast(acc[ct][i] + sbg[col]) * sAlive[row];
                catB[row * WDS + 64 + col] = f2bf(g);
            }
    }
    __syncthreads();
    {   // phase H
        f32x4 acc[4] = {};
        #pragma unroll
        for (int ks = 0; ks < 4; ++ks) {
            const bf16x8 av = *(const bf16x8*)&catB[(m0 + (l & 15)) * WDS + ks * 32 + kseg];
            #pragma unroll
            for (int ct = 0; ct < 4; ++ct) {
                const bf16x8 bv = *(const bf16x8*)&sWdT[(ct * 16 + (l & 15)) * WDS + ks * 32 + kseg];
                acc[ct] = __builtin_amdgcn_mfma_f32_16x16x32_bf16(av, bv, acc[ct], 0, 0, 0);
            }
        }
        #pragma unroll
        for (int ct = 0; ct < 4; ++ct)
            #pragma unroll
            for (int i = 0; i < 4; ++i) {
                const int row = m0 + (l >> 4) * 4 + i;
                const int col = ct * 16 + (l & 15);
                sH[row * HS + col] = fmaxf(acc[ct][i] + sbd[col], 0.f);
            }
    }
    __syncthreads();
    {   // phase O
        const int r = t >> 2, d = t & 3;
        const int j = j0 + r;
        float s = sbo[d];
        #pragma unroll 8
        for (int f = 0; f < 64; ++f) s += sH[r * HS + f] * sWo[f * 4 + d];
        const float segl = ts[((((size_t)b * TT + 4) << 12) + j) * 4 + d];
        out[((((size_t)b << 12) + j) << 2) + d] = segl + tanh_fast(s);
    }
}

// ---------------- launcher ----------------------------------------------------------------
extern "C" void kernel_launch(void* const* d_in, const int* in_sizes, int n_in,
                              void* d_out, int out_size, void* d_ws, size_t ws_size,
                              hipStream_t stream)
{
    (void)in_sizes; (void)n_in; (void)out_size; (void)ws_size;
    const float* ts    = (const float*)d_in[0];
    const int*   edges = (const int*)d_in[1];
    const float* Wc1   = (const float*)d_in[2];
    const float* bc1   = (const float*)d_in[3];
    const float* Wc2   = (const float*)d_in[4];
    const float* bc2   = (const float*)d_in[5];
    const float* Wg1   = (const float*)d_in[6];
    const float* bg    = (const float*)d_in[7];
    const float* Wd    = (const float*)d_in[8];
    const float* bd    = (const float*)d_in[9];
    const float* Wo    = (const float*)d_in[10];
    const float* bo    = (const float*)d_in[11];
    float* out = (float*)d_out;

    char* ws = (char*)d_ws;
    ushort_t* condP   = (ushort_t*)(ws);                              // 2 MiB
    ushort_t* condB   = (ushort_t*)(ws + (size_t)(2 << 20));          // 2 MiB
    float*    agg0    = (float*)(ws + (size_t)(4 << 20));             // 4 MiB
    float*    agg1    = (float*)(ws + (size_t)(8 << 20));             // 4 MiB
    float*    agg2    = (float*)(ws + (size_t)(12 << 20));            // 4 MiB
    float*    agg3    = (float*)(ws + (size_t)(16 << 20));            // 4 MiB
    int*      degI    = (int*)(ws + (size_t)(20 << 20));              // 16 KiB
    uint_t*   colbits = (uint_t*)(ws + (size_t)(20 << 20) + 16384);   // 512 B
    unsigned char* diagB = (unsigned char*)(ws + (size_t)(20 << 20) + 16896); // 4 KiB
    uint_t*   bits    = (uint_t*)(ws + (size_t)(21 << 20));           // 2 MiB packed adjacency

    hipMemsetAsync(colbits, 0, 512, stream);
    k2_bits<<<512, 1024, 0, stream>>>((const int4*)edges, bits, degI, colbits, diagB);
    k1_cond<<<dim3(64, 4), 256, 0, stream>>>(ts, Wc1, bc1, Wc2, bc2, condP, condB);
    k3_gemm<<<512, 1024, 0, stream>>>(bits, condP, agg0, agg1, agg2, agg3);
    k4_mlp<<<dim3(64, 4), 256, 0, stream>>>(ts, condB, agg0, agg1, agg2, agg3,
                                            degI, colbits, diagB,
                                            Wg1, bg, Wd, bd, Wo, bo, out);
}